// Round 2
// baseline (461.777 us; speedup 1.0000x reference)
//
#include <hip/hip_runtime.h>
#include <math.h>

#define Cc 32
#define CH 16                 // channels per half-block
#define Hc 128
#define Wc 160
#define Dc 48
#define HWc (Hc*Wc)
#define TS 16
#define HALO (TS+2)           // 18
#define NPOS (HALO*HALO)      // 324
#define DCHUNK 8
#define NCHUNK (Dc/DCHUNK)    // 6
#define VSTR4 5               // var row stride in float4 (20 floats = 80B, pads 16ch)

// ---------------- kernel 1: projection matrices + weight repack ----------------
// proj: (1,3,4,4). wsproj: rot(9)+trans(3) per src view.
// w2: [half(2)][khkw(9)][kd(3)][c(16)] = 864 floats, float4-readable.
__global__ void k_proj(const float* __restrict__ proj, const float* __restrict__ wreg,
                       float* __restrict__ wsproj, float* __restrict__ w2) {
    const int tid = threadIdx.x;
    // weight repack (all 64 threads)
    for (int i = tid; i < 2 * 9 * 3 * CH; i += 64) {
        int c = i & 15;
        int t = i >> 4;          // (half*9+khkw)*3 + kd
        int kd = t % 3;
        int t2 = t / 3;          // half*9 + khkw
        int khkw = t2 % 9;
        int half = t2 / 9;
        int ch = half * CH + c;
        w2[i] = wreg[ch * 27 + kd * 9 + khkw];
    }
    if (tid != 0) return;
    float a[4][8];
    for (int i = 0; i < 4; i++)
        for (int j = 0; j < 4; j++) {
            a[i][j]     = proj[i * 4 + j];
            a[i][j + 4] = (i == j) ? 1.f : 0.f;
        }
    for (int col = 0; col < 4; col++) {
        int piv = col; float best = fabsf(a[col][col]);
        for (int r = col + 1; r < 4; r++) {
            float v = fabsf(a[r][col]);
            if (v > best) { best = v; piv = r; }
        }
        if (piv != col)
            for (int j = 0; j < 8; j++) { float t = a[col][j]; a[col][j] = a[piv][j]; a[piv][j] = t; }
        float inv = 1.f / a[col][col];
        for (int j = 0; j < 8; j++) a[col][j] *= inv;
        for (int r = 0; r < 4; r++) if (r != col) {
            float f = a[r][col];
            for (int j = 0; j < 8; j++) a[r][j] -= f * a[col][j];
        }
    }
    for (int v = 1; v < 3; v++) {
        const float* P = proj + v * 16;
        float M[3][4];
        for (int i = 0; i < 3; i++)
            for (int j = 0; j < 4; j++) {
                float s = 0.f;
                for (int k = 0; k < 4; k++) s += P[i * 4 + k] * a[k][4 + j];
                M[i][j] = s;
            }
        float* o = wsproj + (v - 1) * 12;
        o[0] = M[0][0]; o[1] = M[0][1]; o[2] = M[0][2];
        o[3] = M[1][0]; o[4] = M[1][1]; o[5] = M[1][2];
        o[6] = M[2][0]; o[7] = M[2][1]; o[8] = M[2][2];
        o[9] = M[0][3]; o[10] = M[1][3]; o[11] = M[2][3];
    }
}

// ---------------- kernel 1b: CHW -> HWC transpose of the 3 feature maps ----------------
__global__ void k_transpose(const float* __restrict__ f0, const float* __restrict__ f1,
                            const float* __restrict__ f2, float* __restrict__ o0,
                            float* __restrict__ o1, float* __restrict__ o2) {
    const int p = blockIdx.x * 256 + threadIdx.x;   // pixel
    if (p >= HWc) return;
    const float* f = (blockIdx.y == 0) ? f0 : (blockIdx.y == 1) ? f1 : f2;
    float*       o = (blockIdx.y == 0) ? o0 : (blockIdx.y == 1) ? o1 : o2;
    float v[Cc];
#pragma unroll
    for (int c = 0; c < Cc; c++) v[c] = f[c * HWc + p];   // coalesced across lanes
    float4* o4 = (float4*)(o + (size_t)p * Cc);
#pragma unroll
    for (int j = 0; j < 8; j++)
        o4[j] = make_float4(v[4 * j], v[4 * j + 1], v[4 * j + 2], v[4 * j + 3]);
}

// ---------------- kernel 2: fused warp + variance + 3D conv (per channel half) ----------------
__global__ __launch_bounds__(256, 4) void k_cost(
    const float* __restrict__ fT0, const float* __restrict__ fT1, const float* __restrict__ fT2,
    const float* __restrict__ dvals, const float4* __restrict__ w2_4,
    const float* __restrict__ wsproj, float* __restrict__ costA, float* __restrict__ costB)
{
    __shared__ float4 var_l[NPOS * VSTR4];
    __shared__ float projl[24];

    const int tid = threadIdx.x;
    if (tid < 24) projl[tid] = wsproj[tid];
    __syncthreads();

    const int tileX = blockIdx.x;                 // 0..9
    const int tileY = blockIdx.y;                 // 0..7
    const int half  = blockIdx.z & 1;             // channel half
    const int d0    = (blockIdx.z >> 1) * DCHUNK;
    const int tx = tid & 15, ty = tid >> 4;
    const int baseH = tileY * TS - 1, baseW = tileX * TS - 1;
    const int cofs = half * (CH / 4);             // float4 offset into 32-ch pixel record

    const float4* fT0_4 = (const float4*)fT0;
    const float4* fT1_4 = (const float4*)fT1;
    const float4* fT2_4 = (const float4*)fT2;

    // two halo positions per thread (324 positions, 256 threads)
    float rx[2][2], ry[2][2], rz[2][2];
    bool  inimg[2];
    int   ridx[2];
    for (int s = 0; s < 2; s++) {
        int p = tid + s * 256;
        bool act = p < NPOS;
        int pp = act ? p : 0;
        int py = pp / HALO, px = pp % HALO;
        int hy = baseH + py, hx = baseW + px;
        inimg[s] = act && hy >= 0 && hy < Hc && hx >= 0 && hx < Wc;
        ridx[s] = inimg[s] ? (hy * Wc + hx) : 0;
        for (int v = 0; v < 2; v++) {
            const float* R = projl + v * 12;
            rx[s][v] = R[0] * hx + R[1] * hy + R[2];
            ry[s][v] = R[3] * hx + R[4] * hy + R[5];
            rz[s][v] = R[6] * hx + R[7] * hy + R[8];
        }
    }

    float cost[DCHUNK];
#pragma unroll
    for (int i = 0; i < DCHUNK; i++) cost[i] = 0.f;

    const int convbase = (ty * HALO + tx) * VSTR4;   // float4 index of (ty,tx)

    for (int dp = d0 - 1; dp <= d0 + DCHUNK; dp++) {
        if (dp < 0 || dp >= Dc) continue;            // uniform across block
        const float depth = dvals[dp];
        __syncthreads();                             // prior conv reads finished

        // ---- variance slice into LDS ----
        for (int s = 0; s < 2; s++) {
            int p = tid + s * 256;
            if (p >= NPOS) break;
            if (!inimg[s]) {
                float4 z = make_float4(0.f, 0.f, 0.f, 0.f);
#pragma unroll
                for (int cc = 0; cc < 4; cc++) var_l[p * VSTR4 + cc] = z;
            } else {
                float cw[2][4]; int ci[2][4];
                for (int v = 0; v < 2; v++) {
                    const float* R = projl + v * 12;
                    float X = fmaf(rx[s][v], depth, R[9]);
                    float Y = fmaf(ry[s][v], depth, R[10]);
                    float Z = fmaf(rz[s][v], depth, R[11]);
                    float iz = 1.f / Z;
                    float gx = X * iz, gy = Y * iz;
                    float x0f = floorf(gx), y0f = floorf(gy);
                    float wx = gx - x0f, wy = gy - y0f;
                    int x0 = (int)x0f, y0 = (int)y0f;
                    bool vx0 = (x0 >= 0) & (x0 <= Wc - 1);
                    bool vx1 = (x0 + 1 >= 0) & (x0 + 1 <= Wc - 1);
                    bool vy0 = (y0 >= 0) & (y0 <= Hc - 1);
                    bool vy1 = (y0 + 1 >= 0) & (y0 + 1 <= Hc - 1);
                    int xc0 = min(max(x0, 0), Wc - 1), xc1 = min(max(x0 + 1, 0), Wc - 1);
                    int yc0 = min(max(y0, 0), Hc - 1), yc1 = min(max(y0 + 1, 0), Hc - 1);
                    cw[v][0] = (1.f - wx) * (1.f - wy) * ((vx0 && vy0) ? 1.f : 0.f);
                    cw[v][1] = wx * (1.f - wy) * ((vx1 && vy0) ? 1.f : 0.f);
                    cw[v][2] = (1.f - wx) * wy * ((vx0 && vy1) ? 1.f : 0.f);
                    cw[v][3] = wx * wy * ((vx1 && vy1) ? 1.f : 0.f);
                    ci[v][0] = (yc0 * Wc + xc0) * 8; ci[v][1] = (yc0 * Wc + xc1) * 8;
                    ci[v][2] = (yc1 * Wc + xc0) * 8; ci[v][3] = (yc1 * Wc + xc1) * 8;
                }
                const int rr = ridx[s] * 8;
#pragma unroll
                for (int cc = 0; cc < 4; cc++) {
                    const int co = cofs + cc;
                    float4 rf  = fT0_4[rr + co];
                    float4 t00 = fT1_4[ci[0][0] + co];
                    float4 t01 = fT1_4[ci[0][1] + co];
                    float4 t10 = fT1_4[ci[0][2] + co];
                    float4 t11 = fT1_4[ci[0][3] + co];
                    float4 u00 = fT2_4[ci[1][0] + co];
                    float4 u01 = fT2_4[ci[1][1] + co];
                    float4 u10 = fT2_4[ci[1][2] + co];
                    float4 u11 = fT2_4[ci[1][3] + co];
                    float4 a1, a2, vr;
                    a1.x = cw[0][0]*t00.x + cw[0][1]*t01.x + cw[0][2]*t10.x + cw[0][3]*t11.x;
                    a1.y = cw[0][0]*t00.y + cw[0][1]*t01.y + cw[0][2]*t10.y + cw[0][3]*t11.y;
                    a1.z = cw[0][0]*t00.z + cw[0][1]*t01.z + cw[0][2]*t10.z + cw[0][3]*t11.z;
                    a1.w = cw[0][0]*t00.w + cw[0][1]*t01.w + cw[0][2]*t10.w + cw[0][3]*t11.w;
                    a2.x = cw[1][0]*u00.x + cw[1][1]*u01.x + cw[1][2]*u10.x + cw[1][3]*u11.x;
                    a2.y = cw[1][0]*u00.y + cw[1][1]*u01.y + cw[1][2]*u10.y + cw[1][3]*u11.y;
                    a2.z = cw[1][0]*u00.z + cw[1][1]*u01.z + cw[1][2]*u10.z + cw[1][3]*u11.z;
                    a2.w = cw[1][0]*u00.w + cw[1][1]*u01.w + cw[1][2]*u10.w + cw[1][3]*u11.w;
                    float smx = rf.x + a1.x + a2.x, sqx = rf.x*rf.x + a1.x*a1.x + a2.x*a2.x;
                    float smy = rf.y + a1.y + a2.y, sqy = rf.y*rf.y + a1.y*a1.y + a2.y*a2.y;
                    float smz = rf.z + a1.z + a2.z, sqz = rf.z*rf.z + a1.z*a1.z + a2.z*a2.z;
                    float smw = rf.w + a1.w + a2.w, sqw = rf.w*rf.w + a1.w*a1.w + a2.w*a2.w;
                    vr.x = sqx * (1.f/3.f) - smx*smx * (1.f/9.f);
                    vr.y = sqy * (1.f/3.f) - smy*smy * (1.f/9.f);
                    vr.z = sqz * (1.f/3.f) - smz*smz * (1.f/9.f);
                    vr.w = sqw * (1.f/3.f) - smw*smw * (1.f/9.f);
                    var_l[p * VSTR4 + cc] = vr;
                }
            }
        }
        __syncthreads();

        // ---- 3x3 spatial conv for the three kd planes over 16 channels ----
        float a0 = 0.f, a1 = 0.f, a2 = 0.f;
        const int wbase = half * 108;   // float4 units: half*9*3*4
#pragma unroll
        for (int k = 0; k < 9; k++) {
            const int off = (k / 3) * HALO + (k % 3);    // compile-time per unrolled k
#pragma unroll
            for (int cc = 0; cc < 4; cc++) {
                float4 v  = var_l[convbase + off * VSTR4 + cc];
                float4 w0 = w2_4[wbase + k * 12 + 0 * 4 + cc];
                float4 w1 = w2_4[wbase + k * 12 + 1 * 4 + cc];
                float4 w2v = w2_4[wbase + k * 12 + 2 * 4 + cc];
                a0 = fmaf(v.x, w0.x, a0); a0 = fmaf(v.y, w0.y, a0);
                a0 = fmaf(v.z, w0.z, a0); a0 = fmaf(v.w, w0.w, a0);
                a1 = fmaf(v.x, w1.x, a1); a1 = fmaf(v.y, w1.y, a1);
                a1 = fmaf(v.z, w1.z, a1); a1 = fmaf(v.w, w1.w, a1);
                a2 = fmaf(v.x, w2v.x, a2); a2 = fmaf(v.y, w2v.y, a2);
                a2 = fmaf(v.z, w2v.z, a2); a2 = fmaf(v.w, w2v.w, a2);
            }
        }
        // cost(d) = A0(d-1) + A1(d) + A2(d+1)
        int r;
        r = dp + 1 - d0; if (r >= 0 && r < DCHUNK) cost[r] += a0;
        r = dp - d0;     if (r >= 0 && r < DCHUNK) cost[r] += a1;
        r = dp - 1 - d0; if (r >= 0 && r < DCHUNK) cost[r] += a2;
    }

    float* outv = half ? costB : costA;
    const int h = tileY * TS + ty, w = tileX * TS + tx;
#pragma unroll
    for (int i = 0; i < DCHUNK; i++)
        outv[(d0 + i) * HWc + h * Wc + w] = cost[i];
}

// ---------------- kernel 3: softmax over depth + regression ----------------
__global__ void k_softmax(const float* __restrict__ costA, const float* __restrict__ costB,
                          const float* __restrict__ dvals, const float* __restrict__ breg,
                          float* __restrict__ out)
{
    const int px = blockIdx.x * 256 + threadIdx.x;
    if (px >= HWc) return;
    const float bias = breg[0];
    float c[Dc];
    float m = -1e30f;
#pragma unroll
    for (int d = 0; d < Dc; d++) {
        c[d] = costA[d * HWc + px] + costB[d * HWc + px] + bias;
        m = fmaxf(m, c[d]);
    }
    float se = 0.f, sed = 0.f, me = 0.f;
#pragma unroll
    for (int d = 0; d < Dc; d++) {
        float e = __expf(c[d] - m);
        se += e;
        sed = fmaf(e, dvals[d], sed);
        me = fmaxf(me, e);
    }
    float inv = 1.f / se;
    out[px]       = sed * inv;   // depth
    out[HWc + px] = me * inv;    // photometric confidence
}

extern "C" void kernel_launch(void* const* d_in, const int* in_sizes, int n_in,
                              void* d_out, int out_size, void* d_ws, size_t ws_size,
                              hipStream_t stream) {
    const float* f0    = (const float*)d_in[0];
    const float* f1    = (const float*)d_in[1];
    const float* f2    = (const float*)d_in[2];
    const float* proj  = (const float*)d_in[3];
    const float* dvals = (const float*)d_in[4];
    const float* wreg  = (const float*)d_in[5];
    const float* breg  = (const float*)d_in[6];

    float* ws      = (float*)d_ws;
    float* wsproj  = ws;                    // 24 floats (pad to 32)
    float* w2      = ws + 32;               // 864 floats
    float* fT0     = ws + 896;              // 655360 floats each
    float* fT1     = fT0 + (size_t)HWc * Cc;
    float* fT2     = fT1 + (size_t)HWc * Cc;
    float* costA   = fT2 + (size_t)HWc * Cc;   // Dc*HWc floats
    float* costB   = costA + (size_t)Dc * HWc;

    k_proj<<<1, 64, 0, stream>>>(proj, wreg, wsproj, w2);
    k_transpose<<<dim3(HWc / 256, 3), 256, 0, stream>>>(f0, f1, f2, fT0, fT1, fT2);

    dim3 grid(Wc / TS, Hc / TS, NCHUNK * 2);   // 10 x 8 x 12 = 960 blocks
    k_cost<<<grid, 256, 0, stream>>>(fT0, fT1, fT2, dvals, (const float4*)w2,
                                     wsproj, costA, costB);

    k_softmax<<<HWc / 256, 256, 0, stream>>>(costA, costB, dvals, breg, (float*)d_out);
}

// Round 3
// 272.522 us; speedup vs baseline: 1.6945x; 1.6945x over previous
//
#include <hip/hip_runtime.h>
#include <math.h>

#define Cc 32
#define CH 16                 // channels per half-block
#define Hc 128
#define Wc 160
#define Dc 48
#define HWc (Hc*Wc)
#define TS 16
#define HALO (TS+2)           // 18
#define NPOS (HALO*HALO)      // 324
#define DCHUNK 8
#define NCHUNK (Dc/DCHUNK)    // 6
#define VSTR4 5               // var row stride in float4 (20 floats = 80B, pads 16ch)

// ---------------- kernel 1: projection matrices + weight repack ----------------
// proj: (1,3,4,4). wsproj: rot(9)+trans(3) per src view.
// w2: [half(2)][khkw(9)][kd(3)][c(16)] = 864 floats, float4-readable.
__global__ void k_proj(const float* __restrict__ proj, const float* __restrict__ wreg,
                       float* __restrict__ wsproj, float* __restrict__ w2) {
    const int tid = threadIdx.x;
    // weight repack (all 64 threads)
    for (int i = tid; i < 2 * 9 * 3 * CH; i += 64) {
        int c = i & 15;
        int t = i >> 4;          // (half*9+khkw)*3 + kd
        int kd = t % 3;
        int t2 = t / 3;          // half*9 + khkw
        int khkw = t2 % 9;
        int half = t2 / 9;
        int ch = half * CH + c;
        w2[i] = wreg[ch * 27 + kd * 9 + khkw];
    }
    if (tid != 0) return;
    float a[4][8];
    for (int i = 0; i < 4; i++)
        for (int j = 0; j < 4; j++) {
            a[i][j]     = proj[i * 4 + j];
            a[i][j + 4] = (i == j) ? 1.f : 0.f;
        }
    for (int col = 0; col < 4; col++) {
        int piv = col; float best = fabsf(a[col][col]);
        for (int r = col + 1; r < 4; r++) {
            float v = fabsf(a[r][col]);
            if (v > best) { best = v; piv = r; }
        }
        if (piv != col)
            for (int j = 0; j < 8; j++) { float t = a[col][j]; a[col][j] = a[piv][j]; a[piv][j] = t; }
        float inv = 1.f / a[col][col];
        for (int j = 0; j < 8; j++) a[col][j] *= inv;
        for (int r = 0; r < 4; r++) if (r != col) {
            float f = a[r][col];
            for (int j = 0; j < 8; j++) a[r][j] -= f * a[col][j];
        }
    }
    for (int v = 1; v < 3; v++) {
        const float* P = proj + v * 16;
        float M[3][4];
        for (int i = 0; i < 3; i++)
            for (int j = 0; j < 4; j++) {
                float s = 0.f;
                for (int k = 0; k < 4; k++) s += P[i * 4 + k] * a[k][4 + j];
                M[i][j] = s;
            }
        float* o = wsproj + (v - 1) * 12;
        o[0] = M[0][0]; o[1] = M[0][1]; o[2] = M[0][2];
        o[3] = M[1][0]; o[4] = M[1][1]; o[5] = M[1][2];
        o[6] = M[2][0]; o[7] = M[2][1]; o[8] = M[2][2];
        o[9] = M[0][3]; o[10] = M[1][3]; o[11] = M[2][3];
    }
}

// ---------------- kernel 1b: CHW -> HWC transpose of the 3 feature maps ----------------
__global__ void k_transpose(const float* __restrict__ f0, const float* __restrict__ f1,
                            const float* __restrict__ f2, float* __restrict__ o0,
                            float* __restrict__ o1, float* __restrict__ o2) {
    const int p = blockIdx.x * 256 + threadIdx.x;   // pixel
    if (p >= HWc) return;
    const float* f = (blockIdx.y == 0) ? f0 : (blockIdx.y == 1) ? f1 : f2;
    float*       o = (blockIdx.y == 0) ? o0 : (blockIdx.y == 1) ? o1 : o2;
    float v[Cc];
#pragma unroll
    for (int c = 0; c < Cc; c++) v[c] = f[c * HWc + p];   // coalesced across lanes
    float4* o4 = (float4*)(o + (size_t)p * Cc);
#pragma unroll
    for (int j = 0; j < 8; j++)
        o4[j] = make_float4(v[4 * j], v[4 * j + 1], v[4 * j + 2], v[4 * j + 3]);
}

// ---------------- kernel 2: fused warp + variance + 3D conv (per channel half) ----------------
// launch_bounds (256,2): 128-VGPR cap. (256,4)=64-VGPR cap caused massive scratch
// spills (679MB WRITE_SIZE, R2). Actual use ~76-100 VGPR -> 4 waves/SIMD anyway.
__global__ __launch_bounds__(256, 2) void k_cost(
    const float* __restrict__ fT0, const float* __restrict__ fT1, const float* __restrict__ fT2,
    const float* __restrict__ dvals, const float4* __restrict__ w2_4,
    const float* __restrict__ wsproj, float* __restrict__ costA, float* __restrict__ costB)
{
    __shared__ float4 var_l[NPOS * VSTR4];
    __shared__ float projl[24];

    const int tid = threadIdx.x;
    if (tid < 24) projl[tid] = wsproj[tid];
    __syncthreads();

    const int tileX = blockIdx.x;                 // 0..9
    const int tileY = blockIdx.y;                 // 0..7
    const int half  = blockIdx.z & 1;             // channel half
    const int d0    = (blockIdx.z >> 1) * DCHUNK;
    const int tx = tid & 15, ty = tid >> 4;
    const int baseH = tileY * TS - 1, baseW = tileX * TS - 1;
    const int cofs = half * (CH / 4);             // float4 offset into 32-ch pixel record

    const float4* fT0_4 = (const float4*)fT0;
    const float4* fT1_4 = (const float4*)fT1;
    const float4* fT2_4 = (const float4*)fT2;

    // two halo positions per thread (324 positions, 256 threads)
    float rx[2][2], ry[2][2], rz[2][2];
    bool  inimg[2];
    int   ridx[2];
    for (int s = 0; s < 2; s++) {
        int p = tid + s * 256;
        bool act = p < NPOS;
        int pp = act ? p : 0;
        int py = pp / HALO, px = pp % HALO;
        int hy = baseH + py, hx = baseW + px;
        inimg[s] = act && hy >= 0 && hy < Hc && hx >= 0 && hx < Wc;
        ridx[s] = inimg[s] ? (hy * Wc + hx) : 0;
        for (int v = 0; v < 2; v++) {
            const float* R = projl + v * 12;
            rx[s][v] = R[0] * hx + R[1] * hy + R[2];
            ry[s][v] = R[3] * hx + R[4] * hy + R[5];
            rz[s][v] = R[6] * hx + R[7] * hy + R[8];
        }
    }

    float cost[DCHUNK];
#pragma unroll
    for (int i = 0; i < DCHUNK; i++) cost[i] = 0.f;

    const int convbase = (ty * HALO + tx) * VSTR4;   // float4 index of (ty,tx)

    for (int dp = d0 - 1; dp <= d0 + DCHUNK; dp++) {
        if (dp < 0 || dp >= Dc) continue;            // uniform across block
        const float depth = dvals[dp];
        __syncthreads();                             // prior conv reads finished

        // ---- variance slice into LDS ----
        for (int s = 0; s < 2; s++) {
            int p = tid + s * 256;
            if (p >= NPOS) break;
            if (!inimg[s]) {
                float4 z = make_float4(0.f, 0.f, 0.f, 0.f);
#pragma unroll
                for (int cc = 0; cc < 4; cc++) var_l[p * VSTR4 + cc] = z;
            } else {
                float cw[2][4]; int ci[2][4];
                for (int v = 0; v < 2; v++) {
                    const float* R = projl + v * 12;
                    float X = fmaf(rx[s][v], depth, R[9]);
                    float Y = fmaf(ry[s][v], depth, R[10]);
                    float Z = fmaf(rz[s][v], depth, R[11]);
                    float iz = 1.f / Z;
                    float gx = X * iz, gy = Y * iz;
                    float x0f = floorf(gx), y0f = floorf(gy);
                    float wx = gx - x0f, wy = gy - y0f;
                    int x0 = (int)x0f, y0 = (int)y0f;
                    bool vx0 = (x0 >= 0) & (x0 <= Wc - 1);
                    bool vx1 = (x0 + 1 >= 0) & (x0 + 1 <= Wc - 1);
                    bool vy0 = (y0 >= 0) & (y0 <= Hc - 1);
                    bool vy1 = (y0 + 1 >= 0) & (y0 + 1 <= Hc - 1);
                    int xc0 = min(max(x0, 0), Wc - 1), xc1 = min(max(x0 + 1, 0), Wc - 1);
                    int yc0 = min(max(y0, 0), Hc - 1), yc1 = min(max(y0 + 1, 0), Hc - 1);
                    cw[v][0] = (1.f - wx) * (1.f - wy) * ((vx0 && vy0) ? 1.f : 0.f);
                    cw[v][1] = wx * (1.f - wy) * ((vx1 && vy0) ? 1.f : 0.f);
                    cw[v][2] = (1.f - wx) * wy * ((vx0 && vy1) ? 1.f : 0.f);
                    cw[v][3] = wx * wy * ((vx1 && vy1) ? 1.f : 0.f);
                    ci[v][0] = (yc0 * Wc + xc0) * 8; ci[v][1] = (yc0 * Wc + xc1) * 8;
                    ci[v][2] = (yc1 * Wc + xc0) * 8; ci[v][3] = (yc1 * Wc + xc1) * 8;
                }
                const int rr = ridx[s] * 8;
#pragma unroll
                for (int cc = 0; cc < 4; cc++) {
                    const int co = cofs + cc;
                    float4 rf  = fT0_4[rr + co];
                    float4 t00 = fT1_4[ci[0][0] + co];
                    float4 t01 = fT1_4[ci[0][1] + co];
                    float4 t10 = fT1_4[ci[0][2] + co];
                    float4 t11 = fT1_4[ci[0][3] + co];
                    float4 u00 = fT2_4[ci[1][0] + co];
                    float4 u01 = fT2_4[ci[1][1] + co];
                    float4 u10 = fT2_4[ci[1][2] + co];
                    float4 u11 = fT2_4[ci[1][3] + co];
                    float4 a1, a2, vr;
                    a1.x = cw[0][0]*t00.x + cw[0][1]*t01.x + cw[0][2]*t10.x + cw[0][3]*t11.x;
                    a1.y = cw[0][0]*t00.y + cw[0][1]*t01.y + cw[0][2]*t10.y + cw[0][3]*t11.y;
                    a1.z = cw[0][0]*t00.z + cw[0][1]*t01.z + cw[0][2]*t10.z + cw[0][3]*t11.z;
                    a1.w = cw[0][0]*t00.w + cw[0][1]*t01.w + cw[0][2]*t10.w + cw[0][3]*t11.w;
                    a2.x = cw[1][0]*u00.x + cw[1][1]*u01.x + cw[1][2]*u10.x + cw[1][3]*u11.x;
                    a2.y = cw[1][0]*u00.y + cw[1][1]*u01.y + cw[1][2]*u10.y + cw[1][3]*u11.y;
                    a2.z = cw[1][0]*u00.z + cw[1][1]*u01.z + cw[1][2]*u10.z + cw[1][3]*u11.z;
                    a2.w = cw[1][0]*u00.w + cw[1][1]*u01.w + cw[1][2]*u10.w + cw[1][3]*u11.w;
                    float smx = rf.x + a1.x + a2.x, sqx = rf.x*rf.x + a1.x*a1.x + a2.x*a2.x;
                    float smy = rf.y + a1.y + a2.y, sqy = rf.y*rf.y + a1.y*a1.y + a2.y*a2.y;
                    float smz = rf.z + a1.z + a2.z, sqz = rf.z*rf.z + a1.z*a1.z + a2.z*a2.z;
                    float smw = rf.w + a1.w + a2.w, sqw = rf.w*rf.w + a1.w*a1.w + a2.w*a2.w;
                    vr.x = sqx * (1.f/3.f) - smx*smx * (1.f/9.f);
                    vr.y = sqy * (1.f/3.f) - smy*smy * (1.f/9.f);
                    vr.z = sqz * (1.f/3.f) - smz*smz * (1.f/9.f);
                    vr.w = sqw * (1.f/3.f) - smw*smw * (1.f/9.f);
                    var_l[p * VSTR4 + cc] = vr;
                }
            }
        }
        __syncthreads();

        // ---- 3x3 spatial conv for the three kd planes over 16 channels ----
        float a0 = 0.f, a1 = 0.f, a2 = 0.f;
        const int wbase = half * 108;   // float4 units: half*9*3*4
#pragma unroll
        for (int k = 0; k < 9; k++) {
            const int off = (k / 3) * HALO + (k % 3);    // compile-time per unrolled k
#pragma unroll
            for (int cc = 0; cc < 4; cc++) {
                float4 v  = var_l[convbase + off * VSTR4 + cc];
                float4 w0 = w2_4[wbase + k * 12 + 0 * 4 + cc];
                float4 w1 = w2_4[wbase + k * 12 + 1 * 4 + cc];
                float4 w2v = w2_4[wbase + k * 12 + 2 * 4 + cc];
                a0 = fmaf(v.x, w0.x, a0); a0 = fmaf(v.y, w0.y, a0);
                a0 = fmaf(v.z, w0.z, a0); a0 = fmaf(v.w, w0.w, a0);
                a1 = fmaf(v.x, w1.x, a1); a1 = fmaf(v.y, w1.y, a1);
                a1 = fmaf(v.z, w1.z, a1); a1 = fmaf(v.w, w1.w, a1);
                a2 = fmaf(v.x, w2v.x, a2); a2 = fmaf(v.y, w2v.y, a2);
                a2 = fmaf(v.z, w2v.z, a2); a2 = fmaf(v.w, w2v.w, a2);
            }
        }
        // cost(d) = A0(d-1) + A1(d) + A2(d+1)
        int r;
        r = dp + 1 - d0; if (r >= 0 && r < DCHUNK) cost[r] += a0;
        r = dp - d0;     if (r >= 0 && r < DCHUNK) cost[r] += a1;
        r = dp - 1 - d0; if (r >= 0 && r < DCHUNK) cost[r] += a2;
    }

    float* outv = half ? costB : costA;
    const int h = tileY * TS + ty, w = tileX * TS + tx;
#pragma unroll
    for (int i = 0; i < DCHUNK; i++)
        outv[(d0 + i) * HWc + h * Wc + w] = cost[i];
}

// ---------------- kernel 3: softmax over depth + regression ----------------
__global__ void k_softmax(const float* __restrict__ costA, const float* __restrict__ costB,
                          const float* __restrict__ dvals, const float* __restrict__ breg,
                          float* __restrict__ out)
{
    const int px = blockIdx.x * 256 + threadIdx.x;
    if (px >= HWc) return;
    const float bias = breg[0];
    float c[Dc];
    float m = -1e30f;
#pragma unroll
    for (int d = 0; d < Dc; d++) {
        c[d] = costA[d * HWc + px] + costB[d * HWc + px] + bias;
        m = fmaxf(m, c[d]);
    }
    float se = 0.f, sed = 0.f, me = 0.f;
#pragma unroll
    for (int d = 0; d < Dc; d++) {
        float e = __expf(c[d] - m);
        se += e;
        sed = fmaf(e, dvals[d], sed);
        me = fmaxf(me, e);
    }
    float inv = 1.f / se;
    out[px]       = sed * inv;   // depth
    out[HWc + px] = me * inv;    // photometric confidence
}

extern "C" void kernel_launch(void* const* d_in, const int* in_sizes, int n_in,
                              void* d_out, int out_size, void* d_ws, size_t ws_size,
                              hipStream_t stream) {
    const float* f0    = (const float*)d_in[0];
    const float* f1    = (const float*)d_in[1];
    const float* f2    = (const float*)d_in[2];
    const float* proj  = (const float*)d_in[3];
    const float* dvals = (const float*)d_in[4];
    const float* wreg  = (const float*)d_in[5];
    const float* breg  = (const float*)d_in[6];

    float* ws      = (float*)d_ws;
    float* wsproj  = ws;                    // 24 floats (pad to 32)
    float* w2      = ws + 32;               // 864 floats
    float* fT0     = ws + 896;              // 655360 floats each
    float* fT1     = fT0 + (size_t)HWc * Cc;
    float* fT2     = fT1 + (size_t)HWc * Cc;
    float* costA   = fT2 + (size_t)HWc * Cc;   // Dc*HWc floats
    float* costB   = costA + (size_t)Dc * HWc;

    k_proj<<<1, 64, 0, stream>>>(proj, wreg, wsproj, w2);
    k_transpose<<<dim3(HWc / 256, 3), 256, 0, stream>>>(f0, f1, f2, fT0, fT1, fT2);

    dim3 grid(Wc / TS, Hc / TS, NCHUNK * 2);   // 10 x 8 x 12 = 960 blocks
    k_cost<<<grid, 256, 0, stream>>>(fT0, fT1, fT2, dvals, (const float4*)w2,
                                     wsproj, costA, costB);

    k_softmax<<<HWc / 256, 256, 0, stream>>>(costA, costB, dvals, breg, (float*)d_out);
}

// Round 4
// 228.140 us; speedup vs baseline: 2.0241x; 1.1945x over previous
//
#include <hip/hip_runtime.h>
#include <math.h>

#define Cc 32
#define CH 16                 // channels per half-block
#define Hc 128
#define Wc 160
#define Dc 48
#define HWc (Hc*Wc)
#define TS 16
#define HALO (TS+2)           // 18
#define NPOS (HALO*HALO)      // 324
#define DCHUNK 8
#define NCHUNK (Dc/DCHUNK)    // 6
#define VSTR4 5               // var row stride in float4 (20 floats = 80B, pads 16ch)
#define NPASS 6               // ceil(NPOS*4 / 256)

// ---------------- kernel 1: projection matrices + weight repack ----------------
__global__ void k_proj(const float* __restrict__ proj, const float* __restrict__ wreg,
                       float* __restrict__ wsproj, float* __restrict__ w2) {
    const int tid = threadIdx.x;
    for (int i = tid; i < 2 * 9 * 3 * CH; i += 64) {
        int c = i & 15;
        int t = i >> 4;          // (half*9+khkw)*3 + kd
        int kd = t % 3;
        int t2 = t / 3;          // half*9 + khkw
        int khkw = t2 % 9;
        int half = t2 / 9;
        int ch = half * CH + c;
        w2[i] = wreg[ch * 27 + kd * 9 + khkw];
    }
    if (tid != 0) return;
    float a[4][8];
    for (int i = 0; i < 4; i++)
        for (int j = 0; j < 4; j++) {
            a[i][j]     = proj[i * 4 + j];
            a[i][j + 4] = (i == j) ? 1.f : 0.f;
        }
    for (int col = 0; col < 4; col++) {
        int piv = col; float best = fabsf(a[col][col]);
        for (int r = col + 1; r < 4; r++) {
            float v = fabsf(a[r][col]);
            if (v > best) { best = v; piv = r; }
        }
        if (piv != col)
            for (int j = 0; j < 8; j++) { float t = a[col][j]; a[col][j] = a[piv][j]; a[piv][j] = t; }
        float inv = 1.f / a[col][col];
        for (int j = 0; j < 8; j++) a[col][j] *= inv;
        for (int r = 0; r < 4; r++) if (r != col) {
            float f = a[r][col];
            for (int j = 0; j < 8; j++) a[r][j] -= f * a[col][j];
        }
    }
    for (int v = 1; v < 3; v++) {
        const float* P = proj + v * 16;
        float M[3][4];
        for (int i = 0; i < 3; i++)
            for (int j = 0; j < 4; j++) {
                float s = 0.f;
                for (int k = 0; k < 4; k++) s += P[i * 4 + k] * a[k][4 + j];
                M[i][j] = s;
            }
        float* o = wsproj + (v - 1) * 12;
        o[0] = M[0][0]; o[1] = M[0][1]; o[2] = M[0][2];
        o[3] = M[1][0]; o[4] = M[1][1]; o[5] = M[1][2];
        o[6] = M[2][0]; o[7] = M[2][1]; o[8] = M[2][2];
        o[9] = M[0][3]; o[10] = M[1][3]; o[11] = M[2][3];
    }
}

// ---------------- kernel 1b: CHW -> HWC transpose of the 3 feature maps ----------------
__global__ void k_transpose(const float* __restrict__ f0, const float* __restrict__ f1,
                            const float* __restrict__ f2, float* __restrict__ o0,
                            float* __restrict__ o1, float* __restrict__ o2) {
    const int p = blockIdx.x * 256 + threadIdx.x;   // pixel
    if (p >= HWc) return;
    const float* f = (blockIdx.y == 0) ? f0 : (blockIdx.y == 1) ? f1 : f2;
    float*       o = (blockIdx.y == 0) ? o0 : (blockIdx.y == 1) ? o1 : o2;
    float v[Cc];
#pragma unroll
    for (int c = 0; c < Cc; c++) v[c] = f[c * HWc + p];   // coalesced across lanes
    float4* o4 = (float4*)(o + (size_t)p * Cc);
#pragma unroll
    for (int j = 0; j < 8; j++)
        o4[j] = make_float4(v[4 * j], v[4 * j + 1], v[4 * j + 2], v[4 * j + 3]);
}

// ---------------- kernel 2: fused warp + variance + 3D conv (per channel half) ----------------
// launch_bounds (256,2): 128-VGPR cap. (256,4)=64-VGPR cap caused massive scratch
// spills (679MB WRITE_SIZE, R2).
// Staging layout: quad of lanes (cc=tid&3) covers one position's 4 float4s so each
// tap is ONE wave-instr hitting 16 coalesced 64B lines (R3 was 4 instrs x 64 lines
// -> TA-bound at VALUBusy=26%).
__global__ __launch_bounds__(256, 2) void k_cost(
    const float* __restrict__ fT0, const float* __restrict__ fT1, const float* __restrict__ fT2,
    const float* __restrict__ dvals, const float4* __restrict__ w2_4,
    const float* __restrict__ wsproj, float* __restrict__ costA, float* __restrict__ costB)
{
    __shared__ float4 var_l[NPOS * VSTR4];
    __shared__ float projl[24];

    const int tid = threadIdx.x;
    if (tid < 24) projl[tid] = wsproj[tid];
    __syncthreads();

    const int tileX = blockIdx.x;                 // 0..9
    const int tileY = blockIdx.y;                 // 0..7
    const int half  = blockIdx.z & 1;             // channel half
    const int d0    = (blockIdx.z >> 1) * DCHUNK;
    const int tx = tid & 15, ty = tid >> 4;
    const int baseH = tileY * TS - 1, baseW = tileX * TS - 1;

    const int posq = tid >> 2;                    // quad id: position within pass
    const int cc   = tid & 3;                     // float4 slot within half-record
    const int co   = half * 4 + cc;               // float4 offset into 32-ch record

    const float4* fT0_4 = (const float4*)fT0;
    const float4* fT1_4 = (const float4*)fT1;
    const float4* fT2_4 = (const float4*)fT2;

    // per-pass position info (pass s covers positions posq + s*64)
    int   ridx6[NPASS];
    float hx6[NPASS], hy6[NPASS];
    int   vmask = 0;
#pragma unroll
    for (int s = 0; s < NPASS; s++) {
        int p = posq + s * 64;
        bool act = p < NPOS;
        int pp = act ? p : 0;
        int py = pp / HALO, px = pp % HALO;
        int hy = baseH + py, hx = baseW + px;
        bool ok = act && hy >= 0 && hy < Hc && hx >= 0 && hx < Wc;
        if (ok) vmask |= (1 << s);
        ridx6[s] = ok ? (hy * Wc + hx) : 0;
        hx6[s] = (float)hx; hy6[s] = (float)hy;
    }

    float cost[DCHUNK];
#pragma unroll
    for (int i = 0; i < DCHUNK; i++) cost[i] = 0.f;

    const int convbase = (ty * HALO + tx) * VSTR4;   // float4 index of (ty,tx)

    for (int dp = d0 - 1; dp <= d0 + DCHUNK; dp++) {
        if (dp < 0 || dp >= Dc) continue;            // uniform across block
        const float depth = dvals[dp];
        __syncthreads();                             // prior conv reads finished

        // ---- variance slice into LDS: one position per lane-quad per pass ----
#pragma unroll
        for (int s = 0; s < NPASS; s++) {
            int p = posq + s * 64;
            if (p >= NPOS) continue;                 // only pass 5, posq>=4
            if (!((vmask >> s) & 1)) {
                var_l[p * VSTR4 + cc] = make_float4(0.f, 0.f, 0.f, 0.f);
                continue;
            }
            const float hx = hx6[s], hy = hy6[s];
            float cw[2][4]; int ci[2][4];
#pragma unroll
            for (int v = 0; v < 2; v++) {
                const float* R = projl + v * 12;
                float rxv = fmaf(R[0], hx, fmaf(R[1], hy, R[2]));
                float ryv = fmaf(R[3], hx, fmaf(R[4], hy, R[5]));
                float rzv = fmaf(R[6], hx, fmaf(R[7], hy, R[8]));
                float X = fmaf(rxv, depth, R[9]);
                float Y = fmaf(ryv, depth, R[10]);
                float Z = fmaf(rzv, depth, R[11]);
                float iz = 1.f / Z;
                float gx = X * iz, gy = Y * iz;
                float x0f = floorf(gx), y0f = floorf(gy);
                float wx = gx - x0f, wy = gy - y0f;
                int x0 = (int)x0f, y0 = (int)y0f;
                bool vx0 = (x0 >= 0) & (x0 <= Wc - 1);
                bool vx1 = (x0 + 1 >= 0) & (x0 + 1 <= Wc - 1);
                bool vy0 = (y0 >= 0) & (y0 <= Hc - 1);
                bool vy1 = (y0 + 1 >= 0) & (y0 + 1 <= Hc - 1);
                int xc0 = min(max(x0, 0), Wc - 1), xc1 = min(max(x0 + 1, 0), Wc - 1);
                int yc0 = min(max(y0, 0), Hc - 1), yc1 = min(max(y0 + 1, 0), Hc - 1);
                cw[v][0] = (1.f - wx) * (1.f - wy) * ((vx0 && vy0) ? 1.f : 0.f);
                cw[v][1] = wx * (1.f - wy) * ((vx1 && vy0) ? 1.f : 0.f);
                cw[v][2] = (1.f - wx) * wy * ((vx0 && vy1) ? 1.f : 0.f);
                cw[v][3] = wx * wy * ((vx1 && vy1) ? 1.f : 0.f);
                ci[v][0] = yc0 * Wc + xc0; ci[v][1] = yc0 * Wc + xc1;
                ci[v][2] = yc1 * Wc + xc0; ci[v][3] = yc1 * Wc + xc1;
            }
            float4 rf  = fT0_4[ridx6[s] * 8 + co];
            float4 t00 = fT1_4[ci[0][0] * 8 + co];
            float4 t01 = fT1_4[ci[0][1] * 8 + co];
            float4 t10 = fT1_4[ci[0][2] * 8 + co];
            float4 t11 = fT1_4[ci[0][3] * 8 + co];
            float4 u00 = fT2_4[ci[1][0] * 8 + co];
            float4 u01 = fT2_4[ci[1][1] * 8 + co];
            float4 u10 = fT2_4[ci[1][2] * 8 + co];
            float4 u11 = fT2_4[ci[1][3] * 8 + co];
            float4 a1, a2, vr;
            a1.x = cw[0][0]*t00.x + cw[0][1]*t01.x + cw[0][2]*t10.x + cw[0][3]*t11.x;
            a1.y = cw[0][0]*t00.y + cw[0][1]*t01.y + cw[0][2]*t10.y + cw[0][3]*t11.y;
            a1.z = cw[0][0]*t00.z + cw[0][1]*t01.z + cw[0][2]*t10.z + cw[0][3]*t11.z;
            a1.w = cw[0][0]*t00.w + cw[0][1]*t01.w + cw[0][2]*t10.w + cw[0][3]*t11.w;
            a2.x = cw[1][0]*u00.x + cw[1][1]*u01.x + cw[1][2]*u10.x + cw[1][3]*u11.x;
            a2.y = cw[1][0]*u00.y + cw[1][1]*u01.y + cw[1][2]*u10.y + cw[1][3]*u11.y;
            a2.z = cw[1][0]*u00.z + cw[1][1]*u01.z + cw[1][2]*u10.z + cw[1][3]*u11.z;
            a2.w = cw[1][0]*u00.w + cw[1][1]*u01.w + cw[1][2]*u10.w + cw[1][3]*u11.w;
            float smx = rf.x + a1.x + a2.x, sqx = rf.x*rf.x + a1.x*a1.x + a2.x*a2.x;
            float smy = rf.y + a1.y + a2.y, sqy = rf.y*rf.y + a1.y*a1.y + a2.y*a2.y;
            float smz = rf.z + a1.z + a2.z, sqz = rf.z*rf.z + a1.z*a1.z + a2.z*a2.z;
            float smw = rf.w + a1.w + a2.w, sqw = rf.w*rf.w + a1.w*a1.w + a2.w*a2.w;
            vr.x = sqx * (1.f/3.f) - smx*smx * (1.f/9.f);
            vr.y = sqy * (1.f/3.f) - smy*smy * (1.f/9.f);
            vr.z = sqz * (1.f/3.f) - smz*smz * (1.f/9.f);
            vr.w = sqw * (1.f/3.f) - smw*smw * (1.f/9.f);
            var_l[p * VSTR4 + cc] = vr;
        }
        __syncthreads();

        // ---- 3x3 spatial conv for the three kd planes over 16 channels ----
        float a0 = 0.f, a1 = 0.f, a2 = 0.f;
        const int wbase = half * 108;   // float4 units: half*9*3*4
#pragma unroll
        for (int k = 0; k < 9; k++) {
            const int off = (k / 3) * HALO + (k % 3);    // compile-time per unrolled k
#pragma unroll
            for (int c4 = 0; c4 < 4; c4++) {
                float4 v  = var_l[convbase + off * VSTR4 + c4];
                float4 w0 = w2_4[wbase + k * 12 + 0 * 4 + c4];
                float4 w1 = w2_4[wbase + k * 12 + 1 * 4 + c4];
                float4 w2v = w2_4[wbase + k * 12 + 2 * 4 + c4];
                a0 = fmaf(v.x, w0.x, a0); a0 = fmaf(v.y, w0.y, a0);
                a0 = fmaf(v.z, w0.z, a0); a0 = fmaf(v.w, w0.w, a0);
                a1 = fmaf(v.x, w1.x, a1); a1 = fmaf(v.y, w1.y, a1);
                a1 = fmaf(v.z, w1.z, a1); a1 = fmaf(v.w, w1.w, a1);
                a2 = fmaf(v.x, w2v.x, a2); a2 = fmaf(v.y, w2v.y, a2);
                a2 = fmaf(v.z, w2v.z, a2); a2 = fmaf(v.w, w2v.w, a2);
            }
        }
        // cost(d) = A0(d-1) + A1(d) + A2(d+1)
        int r;
        r = dp + 1 - d0; if (r >= 0 && r < DCHUNK) cost[r] += a0;
        r = dp - d0;     if (r >= 0 && r < DCHUNK) cost[r] += a1;
        r = dp - 1 - d0; if (r >= 0 && r < DCHUNK) cost[r] += a2;
    }

    float* outv = half ? costB : costA;
    const int h = tileY * TS + ty, w = tileX * TS + tx;
#pragma unroll
    for (int i = 0; i < DCHUNK; i++)
        outv[(d0 + i) * HWc + h * Wc + w] = cost[i];
}

// ---------------- kernel 3: softmax over depth + regression ----------------
__global__ void k_softmax(const float* __restrict__ costA, const float* __restrict__ costB,
                          const float* __restrict__ dvals, const float* __restrict__ breg,
                          float* __restrict__ out)
{
    const int px = blockIdx.x * 256 + threadIdx.x;
    if (px >= HWc) return;
    const float bias = breg[0];
    float c[Dc];
    float m = -1e30f;
#pragma unroll
    for (int d = 0; d < Dc; d++) {
        c[d] = costA[d * HWc + px] + costB[d * HWc + px] + bias;
        m = fmaxf(m, c[d]);
    }
    float se = 0.f, sed = 0.f, me = 0.f;
#pragma unroll
    for (int d = 0; d < Dc; d++) {
        float e = __expf(c[d] - m);
        se += e;
        sed = fmaf(e, dvals[d], sed);
        me = fmaxf(me, e);
    }
    float inv = 1.f / se;
    out[px]       = sed * inv;   // depth
    out[HWc + px] = me * inv;    // photometric confidence
}

extern "C" void kernel_launch(void* const* d_in, const int* in_sizes, int n_in,
                              void* d_out, int out_size, void* d_ws, size_t ws_size,
                              hipStream_t stream) {
    const float* f0    = (const float*)d_in[0];
    const float* f1    = (const float*)d_in[1];
    const float* f2    = (const float*)d_in[2];
    const float* proj  = (const float*)d_in[3];
    const float* dvals = (const float*)d_in[4];
    const float* wreg  = (const float*)d_in[5];
    const float* breg  = (const float*)d_in[6];

    float* ws      = (float*)d_ws;
    float* wsproj  = ws;                    // 24 floats (pad to 32)
    float* w2      = ws + 32;               // 864 floats
    float* fT0     = ws + 896;              // 655360 floats each
    float* fT1     = fT0 + (size_t)HWc * Cc;
    float* fT2     = fT1 + (size_t)HWc * Cc;
    float* costA   = fT2 + (size_t)HWc * Cc;   // Dc*HWc floats
    float* costB   = costA + (size_t)Dc * HWc;

    k_proj<<<1, 64, 0, stream>>>(proj, wreg, wsproj, w2);
    k_transpose<<<dim3(HWc / 256, 3), 256, 0, stream>>>(f0, f1, f2, fT0, fT1, fT2);

    dim3 grid(Wc / TS, Hc / TS, NCHUNK * 2);   // 10 x 8 x 12 = 960 blocks
    k_cost<<<grid, 256, 0, stream>>>(fT0, fT1, fT2, dvals, (const float4*)w2,
                                     wsproj, costA, costB);

    k_softmax<<<HWc / 256, 256, 0, stream>>>(costA, costB, dvals, breg, (float*)d_out);
}